// Round 1
// baseline (4046.523 us; speedup 1.0000x reference)
//
#include <hip/hip_runtime.h>
#include <math.h>

#define D_MODEL 1024
#define NHEADS  16
#define DK      64
#define BATCH   4
#define SEQ     2048
#define MROWS   (BATCH * SEQ)   // 8192

// ---------------------------------------------------------------------------
// NT GEMM body: C[M,N] = X[M,K] @ W[N,K]^T  (torch Linear: x @ W.T)
// 64x64 block tile, 256 threads, 4x4 per thread, K-tile 64, fp32.
// ---------------------------------------------------------------------------
__device__ __forceinline__ void gemm_nt_body(const float* __restrict__ X,
                                             const float* __restrict__ W,
                                             float* __restrict__ C,
                                             int M, int N, int K,
                                             int bmBlk, int bnBlk)
{
    __shared__ float xs[64][68];
    __shared__ float wsh[64][68];

    const int tid = threadIdx.x;
    const int bm = bmBlk * 64;
    const int bn = bnBlk * 64;
    const int ty = tid >> 4, tx = tid & 15;
    const int i0 = ty * 4, j0 = tx * 4;

    float acc[4][4] = {};

    for (int k0 = 0; k0 < K; k0 += 64) {
        // stage 64x64 tiles of X and W (both K-contiguous -> coalesced float4)
#pragma unroll
        for (int r = 0; r < 4; ++r) {
            int f   = tid + 256 * r;
            int row = f >> 4;
            int c4  = (f & 15) << 2;
            float4 xv = *(const float4*)(X + (size_t)(bm + row) * K + k0 + c4);
            float4 wv = *(const float4*)(W + (size_t)(bn + row) * K + k0 + c4);
            *(float4*)&xs[row][c4]  = xv;
            *(float4*)&wsh[row][c4] = wv;
        }
        __syncthreads();

        for (int kk = 0; kk < 64; kk += 4) {
            float a[4][4], b[4][4];
#pragma unroll
            for (int r = 0; r < 4; ++r) {
                float4 t = *(const float4*)&xs[i0 + r][kk];
                a[r][0] = t.x; a[r][1] = t.y; a[r][2] = t.z; a[r][3] = t.w;
            }
#pragma unroll
            for (int c = 0; c < 4; ++c) {
                float4 t = *(const float4*)&wsh[j0 + c][kk];
                b[c][0] = t.x; b[c][1] = t.y; b[c][2] = t.z; b[c][3] = t.w;
            }
#pragma unroll
            for (int r = 0; r < 4; ++r)
#pragma unroll
                for (int c = 0; c < 4; ++c)
#pragma unroll
                    for (int kq = 0; kq < 4; ++kq)
                        acc[r][c] = fmaf(a[r][kq], b[c][kq], acc[r][c]);
        }
        __syncthreads();
    }

#pragma unroll
    for (int r = 0; r < 4; ++r) {
        float4 o = make_float4(acc[r][0], acc[r][1], acc[r][2], acc[r][3]);
        *(float4*)(C + (size_t)(bm + i0 + r) * N + bn + j0) = o;
    }
}

// Fused Q/K/V projection: blockIdx.z picks which of the three GEMMs.
__global__ __launch_bounds__(256)
void proj3_kernel(const float* __restrict__ Q, const float* __restrict__ Kin,
                  const float* __restrict__ V,
                  const float* __restrict__ Wq, const float* __restrict__ Wk,
                  const float* __restrict__ Wv,
                  float* __restrict__ qo, float* __restrict__ ko,
                  float* __restrict__ vo)
{
    const int z = blockIdx.z;
    const float* X = (z == 0) ? Q  : (z == 1) ? Kin : V;
    const float* W = (z == 0) ? Wq : (z == 1) ? Wk  : Wv;
    float*       C = (z == 0) ? qo : (z == 1) ? ko  : vo;
    gemm_nt_body(X, W, C, MROWS, D_MODEL, D_MODEL, blockIdx.x, blockIdx.y);
}

__global__ __launch_bounds__(256)
void gemm_nt_kernel(const float* __restrict__ X, const float* __restrict__ W,
                    float* __restrict__ C, int M, int N, int K)
{
    gemm_nt_body(X, W, C, M, N, K, blockIdx.x, blockIdx.y);
}

// ---------------------------------------------------------------------------
// Flash attention, fp32. Grid: (S/64, NHEADS, BATCH). 256 threads.
// q,k,v laid out [B,S,D_MODEL]; head h occupies columns h*64..h*64+63.
// Output written to [B,S,D_MODEL] (heads re-concatenated) for the out-proj.
// LDS: qs, ks, vs (P is written back into ks after scores are consumed)
// ---------------------------------------------------------------------------
__global__ __launch_bounds__(256)
void attn_kernel(const float* __restrict__ q, const float* __restrict__ k,
                 const float* __restrict__ v, float* __restrict__ o)
{
    __shared__ float qs[64][68];
    __shared__ float ks[64][68];   // also reused for P
    __shared__ float vs[64][68];
    __shared__ float mrow[64], lrow[64];

    const int tid = threadIdx.x;
    const int qt  = blockIdx.x;   // q tile
    const int h   = blockIdx.y;
    const int b   = blockIdx.z;

    const size_t base = ((size_t)b * SEQ) * D_MODEL + (size_t)h * DK;
    const float* qp = q + base + (size_t)qt * 64 * D_MODEL;
    const float* kp = k + base;
    const float* vp = v + base;

    const int ty = tid >> 4, tx = tid & 15;
    const int i0 = ty * 4;        // q-row group owned by this thread
    const int c0 = tx * 4;        // key-col group (score phase) / dk-col group (O phase)

    // stage q tile
#pragma unroll
    for (int r = 0; r < 4; ++r) {
        int f = tid + 256 * r;
        int row = f >> 4, c4 = (f & 15) << 2;
        *(float4*)&qs[row][c4] = *(const float4*)(qp + (size_t)row * D_MODEL + c4);
    }
    if (tid < 64) { mrow[tid] = -INFINITY; lrow[tid] = 0.0f; }

    float accO[4][4] = {};
    __syncthreads();

    for (int kt = 0; kt < SEQ / 64; ++kt) {
        // stage k,v tiles
#pragma unroll
        for (int r = 0; r < 4; ++r) {
            int f = tid + 256 * r;
            int row = f >> 4, c4 = (f & 15) << 2;
            *(float4*)&ks[row][c4] = *(const float4*)(kp + (size_t)(kt * 64 + row) * D_MODEL + c4);
            *(float4*)&vs[row][c4] = *(const float4*)(vp + (size_t)(kt * 64 + row) * D_MODEL + c4);
        }
        __syncthreads();

        // scores: sc[r][c] = (q_row(i0+r) . k_row(c0+c)) * 1/8
        float sc[4][4] = {};
        for (int kk = 0; kk < DK; kk += 4) {
            float a[4][4], bb[4][4];
#pragma unroll
            for (int r = 0; r < 4; ++r) {
                float4 t = *(const float4*)&qs[i0 + r][kk];
                a[r][0] = t.x; a[r][1] = t.y; a[r][2] = t.z; a[r][3] = t.w;
            }
#pragma unroll
            for (int c = 0; c < 4; ++c) {
                float4 t = *(const float4*)&ks[c0 + c][kk];
                bb[c][0] = t.x; bb[c][1] = t.y; bb[c][2] = t.z; bb[c][3] = t.w;
            }
#pragma unroll
            for (int r = 0; r < 4; ++r)
#pragma unroll
                for (int c = 0; c < 4; ++c)
#pragma unroll
                    for (int kq = 0; kq < 4; ++kq)
                        sc[r][c] = fmaf(a[r][kq], bb[c][kq], sc[r][c]);
        }

        // online softmax per row (16 lanes share a row; all within one wave)
        float scl[4];
#pragma unroll
        for (int r = 0; r < 4; ++r) {
            float m = -INFINITY;
#pragma unroll
            for (int c = 0; c < 4; ++c) {
                sc[r][c] *= 0.125f;   // 1/sqrt(64)
                m = fmaxf(m, sc[r][c]);
            }
#pragma unroll
            for (int off = 1; off < 16; off <<= 1)
                m = fmaxf(m, __shfl_xor(m, off, 64));
            float mold = mrow[i0 + r];
            float mnew = fmaxf(mold, m);
            scl[r] = __expf(mold - mnew);
            float rs = 0.0f;
#pragma unroll
            for (int c = 0; c < 4; ++c) {
                sc[r][c] = __expf(sc[r][c] - mnew);
                rs += sc[r][c];
            }
#pragma unroll
            for (int off = 1; off < 16; off <<= 1)
                rs += __shfl_xor(rs, off, 64);
            if (tx == 0) {
                mrow[i0 + r] = mnew;
                lrow[i0 + r] = lrow[i0 + r] * scl[r] + rs;
            }
        }

        __syncthreads();   // everyone done reading ks for scores

        // write P into ks buffer; rescale O accumulator
#pragma unroll
        for (int r = 0; r < 4; ++r) {
#pragma unroll
            for (int c = 0; c < 4; ++c) accO[r][c] *= scl[r];
            *(float4*)&ks[i0 + r][c0] = make_float4(sc[r][0], sc[r][1], sc[r][2], sc[r][3]);
        }
        __syncthreads();

        // accO[r][c] += sum_j P[i0+r][j] * V[j][c0+c]
        for (int j4 = 0; j4 < 64; j4 += 4) {
            float pr[4][4], vj[4][4];
#pragma unroll
            for (int r = 0; r < 4; ++r) {
                float4 t = *(const float4*)&ks[i0 + r][j4];
                pr[r][0] = t.x; pr[r][1] = t.y; pr[r][2] = t.z; pr[r][3] = t.w;
            }
#pragma unroll
            for (int jj = 0; jj < 4; ++jj) {
                float4 t = *(const float4*)&vs[j4 + jj][c0];
                vj[jj][0] = t.x; vj[jj][1] = t.y; vj[jj][2] = t.z; vj[jj][3] = t.w;
            }
#pragma unroll
            for (int r = 0; r < 4; ++r)
#pragma unroll
                for (int c = 0; c < 4; ++c)
#pragma unroll
                    for (int jj = 0; jj < 4; ++jj)
                        accO[r][c] = fmaf(pr[r][jj], vj[jj][c], accO[r][c]);
        }
        __syncthreads();   // protect ks/vs before next staging
    }

    // epilogue: divide by l, write [B,S,D] with head offset
#pragma unroll
    for (int r = 0; r < 4; ++r) {
        float linv = 1.0f / lrow[i0 + r];
        float4 o4 = make_float4(accO[r][0] * linv, accO[r][1] * linv,
                                accO[r][2] * linv, accO[r][3] * linv);
        *(float4*)(o + base + (size_t)(qt * 64 + i0 + r) * D_MODEL + c0) = o4;
    }
}

// ---------------------------------------------------------------------------
extern "C" void kernel_launch(void* const* d_in, const int* in_sizes, int n_in,
                              void* d_out, int out_size, void* d_ws, size_t ws_size,
                              hipStream_t stream)
{
    const float* Q  = (const float*)d_in[0];
    const float* K  = (const float*)d_in[1];
    const float* V  = (const float*)d_in[2];
    const float* Wq = (const float*)d_in[3];
    const float* Wk = (const float*)d_in[4];
    const float* Wv = (const float*)d_in[5];
    const float* Wo = (const float*)d_in[6];
    float* out = (float*)d_out;

    const size_t TENS = (size_t)MROWS * D_MODEL;   // 8.39M floats, 32 MiB
    float* qw = (float*)d_ws;
    float* kw = qw + TENS;
    float* vw = kw + TENS;
    float* aw = vw + TENS;

    dim3 blk(256);

    // 1) fused Q/K/V projections
    proj3_kernel<<<dim3(MROWS / 64, D_MODEL / 64, 3), blk, 0, stream>>>(
        Q, K, V, Wq, Wk, Wv, qw, kw, vw);

    // 2) flash attention per (q-tile, head, batch)
    attn_kernel<<<dim3(SEQ / 64, NHEADS, BATCH), blk, 0, stream>>>(qw, kw, vw, aw);

    // 3) output projection
    gemm_nt_kernel<<<dim3(MROWS / 64, D_MODEL / 64), blk, 0, stream>>>(
        aw, Wo, out, MROWS, D_MODEL, D_MODEL);
}

// Round 2
// 534.705 us; speedup vs baseline: 7.5678x; 7.5678x over previous
//
#include <hip/hip_runtime.h>
#include <math.h>
#include <stdint.h>

#define D_MODEL 1024
#define NHEADS  16
#define DK      64
#define BATCH   4
#define SEQ     2048
#define MROWS   (BATCH * SEQ)              // 8192
#define TENS    ((size_t)MROWS * D_MODEL)  // 8.39M elems
#define WELT    ((size_t)D_MODEL * D_MODEL)

typedef __attribute__((ext_vector_type(8))) _Float16 f16x8;
typedef __attribute__((ext_vector_type(4))) float f32x4;
typedef __attribute__((ext_vector_type(8))) unsigned short us8;
typedef __attribute__((ext_vector_type(4))) unsigned short us4;

__device__ __forceinline__ unsigned short f2h(float x) {
    _Float16 h = (_Float16)x;
    return __builtin_bit_cast(unsigned short, h);
}

// async global->LDS, 16B per lane; LDS dst is wave-uniform base + lane*16
__device__ __forceinline__ void gld_lds16(const void* g, void* l) {
    __builtin_amdgcn_global_load_lds(
        (__attribute__((address_space(1))) void*)(uintptr_t)(g),
        (__attribute__((address_space(3))) void*)(unsigned)(uintptr_t)(l),
        16, 0, 0);
}

// ---------------------------------------------------------------------------
// fp32 -> f16 conversion of all inputs into workspace.
// dst layout: qb,kb,vb (TENS each) then wq,wk,wv,wo (WELT each)
// ---------------------------------------------------------------------------
__global__ __launch_bounds__(256)
void convert_kernel(const float* __restrict__ q, const float* __restrict__ k,
                    const float* __restrict__ v, const float* __restrict__ wq,
                    const float* __restrict__ wk, const float* __restrict__ wv,
                    const float* __restrict__ wo, unsigned short* __restrict__ dst)
{
    const int seg = blockIdx.y;
    const float* src;
    size_t n, doff;
    if (seg < 3) {
        src = (seg == 0) ? q : (seg == 1) ? k : v;
        n = TENS; doff = (size_t)seg * TENS;
    } else {
        src = (seg == 3) ? wq : (seg == 4) ? wk : (seg == 5) ? wv : wo;
        n = WELT; doff = 3 * TENS + (size_t)(seg - 3) * WELT;
    }
    size_t i = ((size_t)blockIdx.x * 256 + threadIdx.x) * 4;
    if (i >= n) return;
    float4 f = *(const float4*)(src + i);
    us4 o = { f2h(f.x), f2h(f.y), f2h(f.z), f2h(f.w) };
    *(us4*)(dst + doff + i) = o;
}

// ---------------------------------------------------------------------------
// f16 MFMA NT GEMM: C[M,N] = A[M,K] @ B[N,K]^T
// 128x128 tile, 256 thr = 4 waves (2x2 of 64x64), BK=64, global_load_lds(16B)
// staging into XOR-swizzled LDS (phys_chunk = log_chunk ^ (row&7) -> 2-way free).
// OMODE: 0 = fp32 row-major, 1 = f16 row-major, 2 = f16 transposed [b,h,d,s]
// ---------------------------------------------------------------------------
template <int OMODE>
__global__ __launch_bounds__(256)
void gemm_f16(const unsigned short* __restrict__ A,
              const unsigned short* __restrict__ B,
              void* __restrict__ C, int M, int N, int K)
{
    __shared__ unsigned short As[128 * 64];
    __shared__ unsigned short Bs[128 * 64];

    const int tid  = threadIdx.x;
    const int wave = tid >> 6;
    const int lane = tid & 63;
    const int g    = lane >> 4;
    const int m15  = lane & 15;
    const int bm   = blockIdx.x * 128;
    const int bn   = blockIdx.y * 128;

    // staging geometry (per wave-instruction: 64 lanes x 16B = 8 rows of 64 f16)
    const int srw = lane >> 3;                 // 0..7 row within chunk-of-8
    const int lc  = (lane & 7) ^ srw;          // logical 16B chunk (swizzle)

    const int wr = (wave >> 1) * 64;
    const int wc = (wave & 1) * 64;

    f32x4 acc[4][4];
#pragma unroll
    for (int i = 0; i < 4; ++i)
#pragma unroll
        for (int j = 0; j < 4; ++j) acc[i][j] = (f32x4){0.f, 0.f, 0.f, 0.f};

    for (int k0 = 0; k0 < K; k0 += 64) {
        __syncthreads();   // prior compute done before overwrite
#pragma unroll
        for (int i = 0; i < 4; ++i) {
            const int rb = wave * 32 + i * 8;          // wave-uniform row base
            gld_lds16(A + (size_t)(bm + rb + srw) * K + k0 + lc * 8,
                      &As[rb * 64]);
            gld_lds16(B + (size_t)(bn + rb + srw) * K + k0 + lc * 8,
                      &Bs[rb * 64]);
        }
        __syncthreads();   // vmcnt(0) drain included

#pragma unroll
        for (int t = 0; t < 2; ++t) {
            f16x8 af[4], bf[4];
#pragma unroll
            for (int i = 0; i < 4; ++i) {
                int row = wr + i * 16 + m15;
                int pc  = (4 * t + g) ^ (row & 7);
                af[i] = *(const f16x8*)&As[row * 64 + pc * 8];
            }
#pragma unroll
            for (int j = 0; j < 4; ++j) {
                int row = wc + j * 16 + m15;
                int pc  = (4 * t + g) ^ (row & 7);
                bf[j] = *(const f16x8*)&Bs[row * 64 + pc * 8];
            }
#pragma unroll
            for (int i = 0; i < 4; ++i)
#pragma unroll
                for (int j = 0; j < 4; ++j)
                    acc[i][j] = __builtin_amdgcn_mfma_f32_16x16x32_f16(
                        af[i], bf[j], acc[i][j], 0, 0, 0);
        }
    }

    // epilogue: C row = bm+wr+i*16+g*4+reg, col = bn+wc+j*16+m15
#pragma unroll
    for (int i = 0; i < 4; ++i) {
        const int gm0 = bm + wr + i * 16 + g * 4;
#pragma unroll
        for (int j = 0; j < 4; ++j) {
            const int gn = bn + wc + j * 16 + m15;
            if (OMODE == 0) {
#pragma unroll
                for (int r = 0; r < 4; ++r)
                    ((float*)C)[(size_t)(gm0 + r) * N + gn] = acc[i][j][r];
            } else if (OMODE == 1) {
#pragma unroll
                for (int r = 0; r < 4; ++r)
                    ((unsigned short*)C)[(size_t)(gm0 + r) * N + gn] = f2h(acc[i][j][r]);
            } else {
                // transposed: vt[b][h][d][s], 4 regs = 4 consecutive s
                const int b_ = gm0 >> 11, s_ = gm0 & 2047;
                const int h_ = gn >> 6,  d_ = gn & 63;
                us4 o = { f2h(acc[i][j][0]), f2h(acc[i][j][1]),
                          f2h(acc[i][j][2]), f2h(acc[i][j][3]) };
                *(us4*)((unsigned short*)C +
                        (((size_t)(b_ * NHEADS + h_) * DK + d_) << 11) + s_) = o;
            }
        }
    }
}

// ---------------------------------------------------------------------------
// Flash attention, f16 MFMA. Grid (SEQ/128, NHEADS, BATCH), 256 thr = 4 waves.
// Wave w owns 32 q-rows (2 m-tiles). K-tile = 64 keys.
// qp,kp: [B,S,D_MODEL] f16 (head h at cols h*64..); vt: [B,H,DK,S] f16.
// Scores: A=Q(m=q), B=K(n=key). PV: out^T: A=V^T(m=d), B=P^T(n=q).
// ---------------------------------------------------------------------------
__global__ __launch_bounds__(256)
void attn_kernel(const unsigned short* __restrict__ qp,
                 const unsigned short* __restrict__ kp,
                 const unsigned short* __restrict__ vt,
                 unsigned short* __restrict__ ao)
{
    __shared__ unsigned short Ks[64 * 72];    // [key][d] padded
    __shared__ unsigned short VTs[64 * 72];   // [d][key] padded
    __shared__ unsigned short Ps[4 * 32 * 72];// per-wave [q][key] padded
    __shared__ float mrow[4][32], lrow[4][32], sclrow[4][32];

    const int tid = threadIdx.x;
    const int w = tid >> 6, lane = tid & 63;
    const int g = lane >> 4, m15 = lane & 15;
    const int qt = blockIdx.x, h = blockIdx.y, b = blockIdx.z;

    const int q0 = qt * 128 + w * 32;
    const size_t rowbase = (size_t)b * SEQ;

    // Q fragments (held whole kernel)
    f16x8 qf[2][2];
#pragma unroll
    for (int mi = 0; mi < 2; ++mi)
#pragma unroll
        for (int t = 0; t < 2; ++t)
            qf[mi][t] = *(const f16x8*)(qp + (rowbase + q0 + mi * 16 + m15) * D_MODEL
                                        + h * DK + t * 32 + g * 8);

    if (lane < 32) { mrow[w][lane] = -INFINITY; lrow[w][lane] = 0.f; }

    f32x4 accO[2][4];
#pragma unroll
    for (int mi = 0; mi < 2; ++mi)
#pragma unroll
        for (int i = 0; i < 4; ++i) accO[mi][i] = (f32x4){0.f, 0.f, 0.f, 0.f};

    const unsigned short* kbase = kp + rowbase * D_MODEL + h * DK;
    const unsigned short* vbase = vt + (size_t)(b * NHEADS + h) * DK * SEQ;

    const int str = tid >> 3;   // staging row 0..31
    const int sch = tid & 7;    // staging chunk

    for (int kt = 0; kt < SEQ / 64; ++kt) {
        __syncthreads();  // previous iteration's LDS reads done (also init vis)
#pragma unroll
        for (int it = 0; it < 2; ++it) {
            int r = str + it * 32;
            *(us8*)&Ks[r * 72 + sch * 8] =
                *(const us8*)(kbase + (size_t)(kt * 64 + r) * D_MODEL + sch * 8);
            *(us8*)&VTs[r * 72 + sch * 8] =
                *(const us8*)(vbase + (size_t)r * SEQ + kt * 64 + sch * 8);
        }
        __syncthreads();

        // scores S[mi][j]: q = mi*16+g*4+reg, key = j*16+m15
        f32x4 S[2][4];
#pragma unroll
        for (int j = 0; j < 4; ++j) {
            f16x8 kf0 = *(const f16x8*)&Ks[(j * 16 + m15) * 72 + g * 8];
            f16x8 kf1 = *(const f16x8*)&Ks[(j * 16 + m15) * 72 + 32 + g * 8];
#pragma unroll
            for (int mi = 0; mi < 2; ++mi) {
                f32x4 z = (f32x4){0.f, 0.f, 0.f, 0.f};
                z = __builtin_amdgcn_mfma_f32_16x16x32_f16(qf[mi][0], kf0, z, 0, 0, 0);
                z = __builtin_amdgcn_mfma_f32_16x16x32_f16(qf[mi][1], kf1, z, 0, 0, 0);
                S[mi][j] = z * 0.125f;   // 1/sqrt(dk)
            }
        }

        // online softmax; stats per q broadcast via LDS
#pragma unroll
        for (int mi = 0; mi < 2; ++mi) {
#pragma unroll
            for (int r = 0; r < 4; ++r) {
                float mx = fmaxf(fmaxf(S[mi][0][r], S[mi][1][r]),
                                 fmaxf(S[mi][2][r], S[mi][3][r]));
                mx = fmaxf(mx, __shfl_xor(mx, 1));
                mx = fmaxf(mx, __shfl_xor(mx, 2));
                mx = fmaxf(mx, __shfl_xor(mx, 4));
                mx = fmaxf(mx, __shfl_xor(mx, 8));
                const int qi = mi * 16 + g * 4 + r;
                float mold = mrow[w][qi];
                float mnew = fmaxf(mold, mx);
                float scl  = __expf(mold - mnew);
                float rs = 0.f;
#pragma unroll
                for (int j = 0; j < 4; ++j) {
                    float p = __expf(S[mi][j][r] - mnew);
                    S[mi][j][r] = p;
                    rs += p;
                }
                rs += __shfl_xor(rs, 1);
                rs += __shfl_xor(rs, 2);
                rs += __shfl_xor(rs, 4);
                rs += __shfl_xor(rs, 8);
                if (m15 == 0) {
                    mrow[w][qi]   = mnew;
                    lrow[w][qi]   = lrow[w][qi] * scl + rs;
                    sclrow[w][qi] = scl;
                }
#pragma unroll
                for (int j = 0; j < 4; ++j)
                    Ps[(w * 32 + qi) * 72 + j * 16 + m15] = f2h(S[mi][j][r]);
            }
        }
        __syncthreads();

        // PV: accO[mi][i] (rows d=i*16+g*4+reg, col q=mi*16+m15)
        f16x8 vf[4][2];
#pragma unroll
        for (int i = 0; i < 4; ++i) {
            vf[i][0] = *(const f16x8*)&VTs[(i * 16 + m15) * 72 + g * 8];
            vf[i][1] = *(const f16x8*)&VTs[(i * 16 + m15) * 72 + 32 + g * 8];
        }
#pragma unroll
        for (int mi = 0; mi < 2; ++mi) {
            const float sq = sclrow[w][mi * 16 + m15];
            f16x8 pf0 = *(const f16x8*)&Ps[(w * 32 + mi * 16 + m15) * 72 + g * 8];
            f16x8 pf1 = *(const f16x8*)&Ps[(w * 32 + mi * 16 + m15) * 72 + 32 + g * 8];
#pragma unroll
            for (int i = 0; i < 4; ++i) {
                f32x4 a = accO[mi][i] * sq;
                a = __builtin_amdgcn_mfma_f32_16x16x32_f16(vf[i][0], pf0, a, 0, 0, 0);
                a = __builtin_amdgcn_mfma_f32_16x16x32_f16(vf[i][1], pf1, a, 0, 0, 0);
                accO[mi][i] = a;
            }
        }
    }

    // epilogue: out^T frag -> ao[b][s][h*64+d]
#pragma unroll
    for (int mi = 0; mi < 2; ++mi) {
        const float li = 1.f / lrow[w][mi * 16 + m15];
        const size_t qg = rowbase + q0 + mi * 16 + m15;
#pragma unroll
        for (int i = 0; i < 4; ++i)
#pragma unroll
            for (int r = 0; r < 4; ++r) {
                int d = i * 16 + g * 4 + r;
                ao[qg * D_MODEL + h * DK + d] = f2h(accO[mi][i][r] * li);
            }
    }
}

// ---------------------------------------------------------------------------
extern "C" void kernel_launch(void* const* d_in, const int* in_sizes, int n_in,
                              void* d_out, int out_size, void* d_ws, size_t ws_size,
                              hipStream_t stream)
{
    const float* Q  = (const float*)d_in[0];
    const float* K  = (const float*)d_in[1];
    const float* V  = (const float*)d_in[2];
    const float* Wq = (const float*)d_in[3];
    const float* Wk = (const float*)d_in[4];
    const float* Wv = (const float*)d_in[5];
    const float* Wo = (const float*)d_in[6];

    unsigned short* base = (unsigned short*)d_ws;
    unsigned short* qb = base;               // f16 inputs
    unsigned short* kb = qb + TENS;
    unsigned short* vb = kb + TENS;
    unsigned short* wq = vb + TENS;          // f16 weights
    unsigned short* wk = wq + WELT;
    unsigned short* wv = wk + WELT;
    unsigned short* wo = wv + WELT;
    unsigned short* qproj = wo + WELT;       // projected q [B,S,D]
    unsigned short* kproj = qproj + TENS;    // projected k [B,S,D]
    unsigned short* vtw   = kproj + TENS;    // projected v transposed [B,H,DK,S]
    unsigned short* aow   = vtw + TENS;      // attention out [B,S,D]

    convert_kernel<<<dim3(TENS / 1024, 7), 256, 0, stream>>>(Q, K, V, Wq, Wk, Wv, Wo, base);

    gemm_f16<1><<<dim3(MROWS / 128, D_MODEL / 128), 256, 0, stream>>>(
        qb, wq, qproj, MROWS, D_MODEL, D_MODEL);
    gemm_f16<1><<<dim3(MROWS / 128, D_MODEL / 128), 256, 0, stream>>>(
        kb, wk, kproj, MROWS, D_MODEL, D_MODEL);
    gemm_f16<2><<<dim3(MROWS / 128, D_MODEL / 128), 256, 0, stream>>>(
        vb, wv, vtw, MROWS, D_MODEL, D_MODEL);

    attn_kernel<<<dim3(SEQ / 128, NHEADS, BATCH), 256, 0, stream>>>(
        qproj, kproj, vtw, aow);

    gemm_f16<0><<<dim3(MROWS / 128, D_MODEL / 128), 256, 0, stream>>>(
        aow, wo, (float*)d_out, MROWS, D_MODEL, D_MODEL);
}

// Round 3
// 374.523 us; speedup vs baseline: 10.8045x; 1.4277x over previous
//
#include <hip/hip_runtime.h>
#include <math.h>
#include <stdint.h>

#define D_MODEL 1024
#define NHEADS  16
#define DK      64
#define BATCH   4
#define SEQ     2048
#define MROWS   (BATCH * SEQ)              // 8192
#define TENS    ((size_t)MROWS * D_MODEL)  // 8.39M elems
#define WELT    ((size_t)D_MODEL * D_MODEL)

typedef __attribute__((ext_vector_type(8))) _Float16 f16x8;
typedef __attribute__((ext_vector_type(4))) float f32x4;
typedef __attribute__((ext_vector_type(8))) unsigned short us8;
typedef __attribute__((ext_vector_type(4))) unsigned short us4;

__device__ __forceinline__ unsigned short f2h(float x) {
    _Float16 h = (_Float16)x;
    return __builtin_bit_cast(unsigned short, h);
}

// async global->LDS, 16B per lane; LDS dst is wave-uniform base + lane*16
__device__ __forceinline__ void gld_lds16(const void* g, void* l) {
    __builtin_amdgcn_global_load_lds(
        (__attribute__((address_space(1))) void*)(uintptr_t)(g),
        (__attribute__((address_space(3))) void*)(unsigned)(uintptr_t)(l),
        16, 0, 0);
}

// ---------------------------------------------------------------------------
// fp32 -> f16 conversion of all inputs into workspace.
// ---------------------------------------------------------------------------
__global__ __launch_bounds__(256)
void convert_kernel(const float* __restrict__ q, const float* __restrict__ k,
                    const float* __restrict__ v, const float* __restrict__ wq,
                    const float* __restrict__ wk, const float* __restrict__ wv,
                    const float* __restrict__ wo, unsigned short* __restrict__ dst)
{
    const int seg = blockIdx.y;
    const float* src;
    size_t n, doff;
    if (seg < 3) {
        src = (seg == 0) ? q : (seg == 1) ? k : v;
        n = TENS; doff = (size_t)seg * TENS;
    } else {
        src = (seg == 3) ? wq : (seg == 4) ? wk : (seg == 5) ? wv : wo;
        n = WELT; doff = 3 * TENS + (size_t)(seg - 3) * WELT;
    }
    size_t i = ((size_t)blockIdx.x * 256 + threadIdx.x) * 4;
    if (i >= n) return;
    float4 f = *(const float4*)(src + i);
    us4 o = { f2h(f.x), f2h(f.y), f2h(f.z), f2h(f.w) };
    *(us4*)(dst + doff + i) = o;
}

// ---------------------------------------------------------------------------
// f16 MFMA NT GEMM: C[M,N] = A[M,K] @ B[N,K]^T  (unchanged from R2)
// OMODE: 0 = fp32 row-major, 1 = f16 row-major, 2 = f16 transposed [b,h,d,s]
// ---------------------------------------------------------------------------
template <int OMODE>
__global__ __launch_bounds__(256)
void gemm_f16(const unsigned short* __restrict__ A,
              const unsigned short* __restrict__ B,
              void* __restrict__ C, int M, int N, int K)
{
    __shared__ unsigned short As[128 * 64];
    __shared__ unsigned short Bs[128 * 64];

    const int tid  = threadIdx.x;
    const int wave = tid >> 6;
    const int lane = tid & 63;
    const int g    = lane >> 4;
    const int m15  = lane & 15;
    const int bm   = blockIdx.x * 128;
    const int bn   = blockIdx.y * 128;

    const int srw = lane >> 3;
    const int lc  = (lane & 7) ^ srw;

    const int wr = (wave >> 1) * 64;
    const int wc = (wave & 1) * 64;

    f32x4 acc[4][4];
#pragma unroll
    for (int i = 0; i < 4; ++i)
#pragma unroll
        for (int j = 0; j < 4; ++j) acc[i][j] = (f32x4){0.f, 0.f, 0.f, 0.f};

    for (int k0 = 0; k0 < K; k0 += 64) {
        __syncthreads();
#pragma unroll
        for (int i = 0; i < 4; ++i) {
            const int rb = wave * 32 + i * 8;
            gld_lds16(A + (size_t)(bm + rb + srw) * K + k0 + lc * 8,
                      &As[rb * 64]);
            gld_lds16(B + (size_t)(bn + rb + srw) * K + k0 + lc * 8,
                      &Bs[rb * 64]);
        }
        __syncthreads();

#pragma unroll
        for (int t = 0; t < 2; ++t) {
            f16x8 af[4], bf[4];
#pragma unroll
            for (int i = 0; i < 4; ++i) {
                int row = wr + i * 16 + m15;
                int pc  = (4 * t + g) ^ (row & 7);
                af[i] = *(const f16x8*)&As[row * 64 + pc * 8];
            }
#pragma unroll
            for (int j = 0; j < 4; ++j) {
                int row = wc + j * 16 + m15;
                int pc  = (4 * t + g) ^ (row & 7);
                bf[j] = *(const f16x8*)&Bs[row * 64 + pc * 8];
            }
#pragma unroll
            for (int i = 0; i < 4; ++i)
#pragma unroll
                for (int j = 0; j < 4; ++j)
                    acc[i][j] = __builtin_amdgcn_mfma_f32_16x16x32_f16(
                        af[i], bf[j], acc[i][j], 0, 0, 0);
        }
    }

#pragma unroll
    for (int i = 0; i < 4; ++i) {
        const int gm0 = bm + wr + i * 16 + g * 4;
#pragma unroll
        for (int j = 0; j < 4; ++j) {
            const int gn = bn + wc + j * 16 + m15;
            if (OMODE == 0) {
#pragma unroll
                for (int r = 0; r < 4; ++r)
                    ((float*)C)[(size_t)(gm0 + r) * N + gn] = acc[i][j][r];
            } else if (OMODE == 1) {
#pragma unroll
                for (int r = 0; r < 4; ++r)
                    ((unsigned short*)C)[(size_t)(gm0 + r) * N + gn] = f2h(acc[i][j][r]);
            } else {
                const int b_ = gm0 >> 11, s_ = gm0 & 2047;
                const int h_ = gn >> 6,  d_ = gn & 63;
                us4 o = { f2h(acc[i][j][0]), f2h(acc[i][j][1]),
                          f2h(acc[i][j][2]), f2h(acc[i][j][3]) };
                *(us4*)((unsigned short*)C +
                        (((size_t)(b_ * NHEADS + h_) * DK + d_) << 11) + s_) = o;
            }
        }
    }
}

// ---------------------------------------------------------------------------
// Flash attention, transposed-score form. Grid (SEQ/128, NHEADS, BATCH),
// 256 thr = 4 waves; wave w owns 32 q-rows. K-tile = 64 keys.
//   S^T = K·Q^T  (A=K from LDS, B=Q in regs)  -> each lane owns whole q-rows
//   online softmax fully in registers (2 shuffles per reduce)
//   O^T = V^T·P^T (A=V^T from LDS, B=P^T via per-wave LDS round-trip)
// qp,kp: [B,S,D_MODEL] f16; vt: [B,H,DK,S] f16; ao: [B,S,D_MODEL] f16
// ---------------------------------------------------------------------------
__global__ __launch_bounds__(256, 4)
void attn_kernel(const unsigned short* __restrict__ qp,
                 const unsigned short* __restrict__ kp,
                 const unsigned short* __restrict__ vt,
                 unsigned short* __restrict__ ao)
{
    __shared__ unsigned short Ks[64 * 64];     // [key][d], XOR-swizzled chunks
    __shared__ unsigned short VTs[64 * 64];    // [d][key], XOR-swizzled chunks
    __shared__ unsigned short Ps[4][32 * 72];  // per-wave P^T as [q][key], padded

    const int tid = threadIdx.x;
    const int w = tid >> 6, lane = tid & 63;
    const int g = lane >> 4, m15 = lane & 15;
    const int qt = blockIdx.x, h = blockIdx.y, b = blockIdx.z;

    const int q0 = qt * 128 + w * 32;
    const size_t rowbase = (size_t)b * SEQ;

    const int srw = lane >> 3;                 // staging row-in-8
    const int lc  = (lane & 7) ^ srw;          // swizzled logical chunk

    // Q fragments (B-operand: n=q=m15, k=d=g*8+j), pre-scaled by 1/sqrt(dk)
    f16x8 qf[2][2];
#pragma unroll
    for (int mi = 0; mi < 2; ++mi)
#pragma unroll
        for (int t = 0; t < 2; ++t) {
            f16x8 v = *(const f16x8*)(qp + (rowbase + q0 + mi * 16 + m15) * D_MODEL
                                      + h * DK + t * 32 + g * 8);
            qf[mi][t] = v * (_Float16)0.125f;
        }

    float mrun[2] = {-INFINITY, -INFINITY};
    float lrun[2] = {0.f, 0.f};

    f32x4 accO[2][4];
#pragma unroll
    for (int mi = 0; mi < 2; ++mi)
#pragma unroll
        for (int i = 0; i < 4; ++i) accO[mi][i] = (f32x4){0.f, 0.f, 0.f, 0.f};

    const unsigned short* kbase = kp + rowbase * D_MODEL + h * DK;
    const unsigned short* vbase = vt + (size_t)(b * NHEADS + h) * DK * SEQ;

    for (int kt = 0; kt < SEQ / 64; ++kt) {
        __syncthreads();   // prior iteration's Ks/VTs reads complete
        // stage K tile [64 keys x 64 d] and V^T tile [64 d x 64 keys]
#pragma unroll
        for (int it = 0; it < 2; ++it) {
            const int rb = w * 16 + it * 8;    // wave-uniform row base
            gld_lds16(kbase + (size_t)(kt * 64 + rb + srw) * D_MODEL + lc * 8,
                      &Ks[rb * 64]);
            gld_lds16(vbase + (size_t)(rb + srw) * SEQ + kt * 64 + lc * 8,
                      &VTs[rb * 64]);
        }
        __syncthreads();   // vmcnt drain + visibility

        // S^T[key][q]: A=K (m=key=m15 per tile), B=Q. ST[km][mi] reg r: key=km*16+g*4+r, q=mi*16+m15
        f32x4 ST[4][2];
#pragma unroll
        for (int km = 0; km < 4; ++km) {
            const int row = km * 16 + m15;
            f16x8 kf0 = *(const f16x8*)&Ks[row * 64 + ((0 + g) ^ (row & 7)) * 8];
            f16x8 kf1 = *(const f16x8*)&Ks[row * 64 + ((4 + g) ^ (row & 7)) * 8];
#pragma unroll
            for (int mi = 0; mi < 2; ++mi) {
                f32x4 z = (f32x4){0.f, 0.f, 0.f, 0.f};
                z = __builtin_amdgcn_mfma_f32_16x16x32_f16(kf0, qf[mi][0], z, 0, 0, 0);
                z = __builtin_amdgcn_mfma_f32_16x16x32_f16(kf1, qf[mi][1], z, 0, 0, 0);
                ST[km][mi] = z;
            }
        }

        // register-resident online softmax (per lane: q = mi*16+m15)
        float scl[2];
#pragma unroll
        for (int mi = 0; mi < 2; ++mi) {
            float mx = -INFINITY;
#pragma unroll
            for (int km = 0; km < 4; ++km)
#pragma unroll
                for (int r = 0; r < 4; ++r) mx = fmaxf(mx, ST[km][mi][r]);
            mx = fmaxf(mx, __shfl_xor(mx, 16));
            mx = fmaxf(mx, __shfl_xor(mx, 32));
            float mnew = fmaxf(mrun[mi], mx);
            scl[mi] = __expf(mrun[mi] - mnew);
            mrun[mi] = mnew;
            float rs = 0.f;
#pragma unroll
            for (int km = 0; km < 4; ++km) {
#pragma unroll
                for (int r = 0; r < 4; ++r) {
                    float p = __expf(ST[km][mi][r] - mnew);
                    ST[km][mi][r] = p;
                    rs += p;
                }
                // write P^T[q][key]: 4 consecutive keys
                us4 o = { f2h(ST[km][mi][0]), f2h(ST[km][mi][1]),
                          f2h(ST[km][mi][2]), f2h(ST[km][mi][3]) };
                *(us4*)&Ps[w][(mi * 16 + m15) * 72 + km * 16 + g * 4] = o;
            }
            rs += __shfl_xor(rs, 16);
            rs += __shfl_xor(rs, 32);
            lrun[mi] = lrun[mi] * scl[mi] + rs;
        }
        // per-wave LDS: intra-wave ordering only, no barrier needed

        // P^T B-frags: n=q=m15, k=key=g*8+j
        f16x8 pf[2][2];
#pragma unroll
        for (int mi = 0; mi < 2; ++mi) {
            pf[mi][0] = *(const f16x8*)&Ps[w][(mi * 16 + m15) * 72 + g * 8];
            pf[mi][1] = *(const f16x8*)&Ps[w][(mi * 16 + m15) * 72 + 32 + g * 8];
        }

        // O^T += V^T·P^T : A=V^T (m=d=m15 per tile, k=key)
#pragma unroll
        for (int i = 0; i < 4; ++i) {
            const int row = i * 16 + m15;
            f16x8 vf0 = *(const f16x8*)&VTs[row * 64 + ((0 + g) ^ (row & 7)) * 8];
            f16x8 vf1 = *(const f16x8*)&VTs[row * 64 + ((4 + g) ^ (row & 7)) * 8];
#pragma unroll
            for (int mi = 0; mi < 2; ++mi) {
                f32x4 a = accO[mi][i] * scl[mi];
                a = __builtin_amdgcn_mfma_f32_16x16x32_f16(vf0, pf[mi][0], a, 0, 0, 0);
                a = __builtin_amdgcn_mfma_f32_16x16x32_f16(vf1, pf[mi][1], a, 0, 0, 0);
                accO[mi][i] = a;
            }
        }
    }

    // epilogue: O^T C-layout row d=i*16+g*4+r, col q=mi*16+m15 -> ao[b][s][h*64+d]
#pragma unroll
    for (int mi = 0; mi < 2; ++mi) {
        const float li = 1.f / lrun[mi];
        const size_t qg = rowbase + q0 + mi * 16 + m15;
#pragma unroll
        for (int i = 0; i < 4; ++i) {
            us4 o = { f2h(accO[mi][i][0] * li), f2h(accO[mi][i][1] * li),
                      f2h(accO[mi][i][2] * li), f2h(accO[mi][i][3] * li) };
            *(us4*)(ao + qg * D_MODEL + h * DK + i * 16 + g * 4) = o;
        }
    }
}

// ---------------------------------------------------------------------------
extern "C" void kernel_launch(void* const* d_in, const int* in_sizes, int n_in,
                              void* d_out, int out_size, void* d_ws, size_t ws_size,
                              hipStream_t stream)
{
    const float* Q  = (const float*)d_in[0];
    const float* K  = (const float*)d_in[1];
    const float* V  = (const float*)d_in[2];
    const float* Wq = (const float*)d_in[3];
    const float* Wk = (const float*)d_in[4];
    const float* Wv = (const float*)d_in[5];
    const float* Wo = (const float*)d_in[6];

    unsigned short* base = (unsigned short*)d_ws;
    unsigned short* qb = base;
    unsigned short* kb = qb + TENS;
    unsigned short* vb = kb + TENS;
    unsigned short* wq = vb + TENS;
    unsigned short* wk = wq + WELT;
    unsigned short* wv = wk + WELT;
    unsigned short* wo = wv + WELT;
    unsigned short* qproj = wo + WELT;
    unsigned short* kproj = qproj + TENS;
    unsigned short* vtw   = kproj + TENS;    // [B,H,DK,S]
    unsigned short* aow   = vtw + TENS;

    convert_kernel<<<dim3(TENS / 1024, 7), 256, 0, stream>>>(Q, K, V, Wq, Wk, Wv, Wo, base);

    gemm_f16<1><<<dim3(MROWS / 128, D_MODEL / 128), 256, 0, stream>>>(
        qb, wq, qproj, MROWS, D_MODEL, D_MODEL);
    gemm_f16<1><<<dim3(MROWS / 128, D_MODEL / 128), 256, 0, stream>>>(
        kb, wk, kproj, MROWS, D_MODEL, D_MODEL);
    gemm_f16<2><<<dim3(MROWS / 128, D_MODEL / 128), 256, 0, stream>>>(
        vb, wv, vtw, MROWS, D_MODEL, D_MODEL);

    attn_kernel<<<dim3(SEQ / 128, NHEADS, BATCH), 256, 0, stream>>>(
        qproj, kproj, vtw, aow);

    gemm_f16<0><<<dim3(MROWS / 128, D_MODEL / 128), 256, 0, stream>>>(
        aow, wo, (float*)d_out, MROWS, D_MODEL, D_MODEL);
}

// Round 5
// 342.502 us; speedup vs baseline: 11.8146x; 1.0935x over previous
//
#include <hip/hip_runtime.h>
#include <math.h>
#include <stdint.h>

#define D_MODEL 1024
#define NHEADS  16
#define DK      64
#define BATCH   4
#define SEQ     2048
#define MROWS   (BATCH * SEQ)              // 8192
#define TENS    ((size_t)MROWS * D_MODEL)  // 8.39M elems
#define WELT    ((size_t)D_MODEL * D_MODEL)

typedef __attribute__((ext_vector_type(8))) _Float16 f16x8;
typedef __attribute__((ext_vector_type(2))) __fp16 h16x2;
typedef __attribute__((ext_vector_type(4))) float f32x4;
typedef __attribute__((ext_vector_type(8))) unsigned short us8;
typedef __attribute__((ext_vector_type(4))) unsigned short us4;

__device__ __forceinline__ unsigned short f2h(float x) {
    _Float16 h = (_Float16)x;
    return __builtin_bit_cast(unsigned short, h);
}

#if __has_builtin(__builtin_amdgcn_exp2f)
__device__ __forceinline__ float fexp2(float x) { return __builtin_amdgcn_exp2f(x); }
#else
__device__ __forceinline__ float fexp2(float x) { return exp2f(x); }
#endif

// async global->LDS, 16B per lane; LDS dst is wave-uniform base + lane*16
__device__ __forceinline__ void gld_lds16(const void* g, void* l) {
    __builtin_amdgcn_global_load_lds(
        (__attribute__((address_space(1))) void*)(uintptr_t)(g),
        (__attribute__((address_space(3))) void*)(unsigned)(uintptr_t)(l),
        16, 0, 0);
}

// ---------------------------------------------------------------------------
// fp32 -> f16 conversion of all inputs into workspace.
// ---------------------------------------------------------------------------
__global__ __launch_bounds__(256)
void convert_kernel(const float* __restrict__ q, const float* __restrict__ k,
                    const float* __restrict__ v, const float* __restrict__ wq,
                    const float* __restrict__ wk, const float* __restrict__ wv,
                    const float* __restrict__ wo, unsigned short* __restrict__ dst)
{
    const int seg = blockIdx.y;
    const float* src;
    size_t n, doff;
    if (seg < 3) {
        src = (seg == 0) ? q : (seg == 1) ? k : v;
        n = TENS; doff = (size_t)seg * TENS;
    } else {
        src = (seg == 3) ? wq : (seg == 4) ? wk : (seg == 5) ? wv : wo;
        n = WELT; doff = 3 * TENS + (size_t)(seg - 3) * WELT;
    }
    size_t i = ((size_t)blockIdx.x * 256 + threadIdx.x) * 4;
    if (i >= n) return;
    float4 f = *(const float4*)(src + i);
    us4 o = { f2h(f.x), f2h(f.y), f2h(f.z), f2h(f.w) };
    *(us4*)(dst + doff + i) = o;
}

// ---------------------------------------------------------------------------
// f16 MFMA NT GEMM body: C[M,N] = A[M,K] @ B[N,K]^T
// 128x128 tile, 256 thr = 4 waves, BK=64, global_load_lds(16B), XOR swizzle.
// omode: 0 = fp32 row-major, 1 = f16 row-major, 2 = f16 transposed [b,h,d,s]
// ---------------------------------------------------------------------------
__device__ __forceinline__
void gemm_body(const unsigned short* __restrict__ A,
               const unsigned short* __restrict__ B,
               void* __restrict__ C, int N, int K, int omode,
               unsigned short* As, unsigned short* Bs)
{
    const int tid  = threadIdx.x;
    const int wave = tid >> 6;
    const int lane = tid & 63;
    const int g    = lane >> 4;
    const int m15  = lane & 15;
    const int bm   = blockIdx.x * 128;
    const int bn   = blockIdx.y * 128;

    const int srw = lane >> 3;
    const int lc  = (lane & 7) ^ srw;

    const int wr = (wave >> 1) * 64;
    const int wc = (wave & 1) * 64;

    f32x4 acc[4][4];
#pragma unroll
    for (int i = 0; i < 4; ++i)
#pragma unroll
        for (int j = 0; j < 4; ++j) acc[i][j] = (f32x4){0.f, 0.f, 0.f, 0.f};

    for (int k0 = 0; k0 < K; k0 += 64) {
        __syncthreads();
#pragma unroll
        for (int i = 0; i < 4; ++i) {
            const int rb = wave * 32 + i * 8;
            gld_lds16(A + (size_t)(bm + rb + srw) * K + k0 + lc * 8,
                      &As[rb * 64]);
            gld_lds16(B + (size_t)(bn + rb + srw) * K + k0 + lc * 8,
                      &Bs[rb * 64]);
        }
        __syncthreads();

#pragma unroll
        for (int t = 0; t < 2; ++t) {
            f16x8 af[4], bf[4];
#pragma unroll
            for (int i = 0; i < 4; ++i) {
                int row = wr + i * 16 + m15;
                int pc  = (4 * t + g) ^ (row & 7);
                af[i] = *(const f16x8*)&As[row * 64 + pc * 8];
            }
#pragma unroll
            for (int j = 0; j < 4; ++j) {
                int row = wc + j * 16 + m15;
                int pc  = (4 * t + g) ^ (row & 7);
                bf[j] = *(const f16x8*)&Bs[row * 64 + pc * 8];
            }
#pragma unroll
            for (int i = 0; i < 4; ++i)
#pragma unroll
                for (int j = 0; j < 4; ++j)
                    acc[i][j] = __builtin_amdgcn_mfma_f32_16x16x32_f16(
                        af[i], bf[j], acc[i][j], 0, 0, 0);
        }
    }

#pragma unroll
    for (int i = 0; i < 4; ++i) {
        const int gm0 = bm + wr + i * 16 + g * 4;
#pragma unroll
        for (int j = 0; j < 4; ++j) {
            const int gn = bn + wc + j * 16 + m15;
            if (omode == 0) {
#pragma unroll
                for (int r = 0; r < 4; ++r)
                    ((float*)C)[(size_t)(gm0 + r) * N + gn] = acc[i][j][r];
            } else if (omode == 1) {
#pragma unroll
                for (int r = 0; r < 4; ++r)
                    ((unsigned short*)C)[(size_t)(gm0 + r) * N + gn] = f2h(acc[i][j][r]);
            } else {
                const int b_ = gm0 >> 11, s_ = gm0 & 2047;
                const int h_ = gn >> 6,  d_ = gn & 63;
                us4 o = { f2h(acc[i][j][0]), f2h(acc[i][j][1]),
                          f2h(acc[i][j][2]), f2h(acc[i][j][3]) };
                *(us4*)((unsigned short*)C +
                        (((size_t)(b_ * NHEADS + h_) * DK + d_) << 11) + s_) = o;
            }
        }
    }
}

// Fused Q/K/V projections in one dispatch: blockIdx.z selects the GEMM.
__global__ __launch_bounds__(256)
void proj3_kernel(const unsigned short* __restrict__ qb,
                  const unsigned short* __restrict__ kb,
                  const unsigned short* __restrict__ vb,
                  const unsigned short* __restrict__ wq,
                  const unsigned short* __restrict__ wk,
                  const unsigned short* __restrict__ wv,
                  unsigned short* __restrict__ qproj,
                  unsigned short* __restrict__ kproj,
                  unsigned short* __restrict__ vtw)
{
    __shared__ unsigned short As[128 * 64];
    __shared__ unsigned short Bs[128 * 64];
    const int z = blockIdx.z;
    const unsigned short* A = (z == 0) ? qb : (z == 1) ? kb : vb;
    const unsigned short* B = (z == 0) ? wq : (z == 1) ? wk : wv;
    void* C = (z == 0) ? (void*)qproj : (z == 1) ? (void*)kproj : (void*)vtw;
    gemm_body(A, B, C, D_MODEL, D_MODEL, (z == 2) ? 2 : 1, As, Bs);
}

__global__ __launch_bounds__(256)
void gemm_out_kernel(const unsigned short* __restrict__ A,
                     const unsigned short* __restrict__ B,
                     float* __restrict__ C)
{
    __shared__ unsigned short As[128 * 64];
    __shared__ unsigned short Bs[128 * 64];
    gemm_body(A, B, C, D_MODEL, D_MODEL, 0, As, Bs);
}

// ---------------------------------------------------------------------------
// Flash attention, transposed-score form, 64 q/wave (mi=4).
// Grid (SEQ/256, NHEADS, BATCH), 256 thr = 4 waves; wave w owns 64 q-rows.
// K-tile = 64 keys.  S^T = K·Q^T (A=K LDS, B=Q regs, log2-domain pre-scale);
// register online softmax (2 shuffles per reduce, exp2);
// O^T = V^T·P^T (A=V^T LDS, B=P^T per-wave LDS round-trip).
// qp,kp: [B,S,D_MODEL] f16; vt: [B,H,DK,S] f16; ao: [B,S,D_MODEL] f16
// ---------------------------------------------------------------------------
__global__ __launch_bounds__(256, 2)
void attn_kernel(const unsigned short* __restrict__ qp,
                 const unsigned short* __restrict__ kp,
                 const unsigned short* __restrict__ vt,
                 unsigned short* __restrict__ ao)
{
    __shared__ unsigned short Ks[64 * 64];     // [key][d], XOR-swizzled
    __shared__ unsigned short VTs[64 * 64];    // [d][key], XOR-swizzled
    __shared__ unsigned short Ps[4][64 * 72];  // per-wave P^T [q][key], padded

    const int tid = threadIdx.x;
    const int w = tid >> 6, lane = tid & 63;
    const int g = lane >> 4, m15 = lane & 15;
    const int qt = blockIdx.x, h = blockIdx.y, b = blockIdx.z;

    const int q0 = qt * 256 + w * 64;
    const size_t rowbase = (size_t)b * SEQ;

    const int srw = lane >> 3;
    const int lc  = (lane & 7) ^ srw;

    // Q fragments (B-operand), pre-scaled by (1/sqrt(dk)) * log2(e)
    const _Float16 qscale = (_Float16)(0.125f * 1.4426950408889634f);
    f16x8 qf[4][2];
#pragma unroll
    for (int mi = 0; mi < 4; ++mi)
#pragma unroll
        for (int t = 0; t < 2; ++t) {
            f16x8 v = *(const f16x8*)(qp + (rowbase + q0 + mi * 16 + m15) * D_MODEL
                                      + h * DK + t * 32 + g * 8);
            qf[mi][t] = v * qscale;
        }

    float mrun[4] = {-INFINITY, -INFINITY, -INFINITY, -INFINITY};
    float lrun[4] = {0.f, 0.f, 0.f, 0.f};

    f32x4 accO[4][4];
#pragma unroll
    for (int mi = 0; mi < 4; ++mi)
#pragma unroll
        for (int i = 0; i < 4; ++i) accO[mi][i] = (f32x4){0.f, 0.f, 0.f, 0.f};

    const unsigned short* kbase = kp + rowbase * D_MODEL + h * DK;
    const unsigned short* vbase = vt + (size_t)(b * NHEADS + h) * DK * SEQ;

    for (int kt = 0; kt < SEQ / 64; ++kt) {
        __syncthreads();   // prior iteration's Ks/VTs reads complete
#pragma unroll
        for (int it = 0; it < 2; ++it) {
            const int rb = w * 16 + it * 8;
            gld_lds16(kbase + (size_t)(kt * 64 + rb + srw) * D_MODEL + lc * 8,
                      &Ks[rb * 64]);
            gld_lds16(vbase + (size_t)(rb + srw) * SEQ + kt * 64 + lc * 8,
                      &VTs[rb * 64]);
        }
        __syncthreads();

        // S^T (log2 domain): ST[km][mi] reg r: key=km*16+g*4+r, q=mi*16+m15
        f32x4 ST[4][4];
#pragma unroll
        for (int km = 0; km < 4; ++km) {
            const int row = km * 16 + m15;
            f16x8 kf0 = *(const f16x8*)&Ks[row * 64 + ((0 + g) ^ (row & 7)) * 8];
            f16x8 kf1 = *(const f16x8*)&Ks[row * 64 + ((4 + g) ^ (row & 7)) * 8];
#pragma unroll
            for (int mi = 0; mi < 4; ++mi) {
                f32x4 z = (f32x4){0.f, 0.f, 0.f, 0.f};
                z = __builtin_amdgcn_mfma_f32_16x16x32_f16(kf0, qf[mi][0], z, 0, 0, 0);
                z = __builtin_amdgcn_mfma_f32_16x16x32_f16(kf1, qf[mi][1], z, 0, 0, 0);
                ST[km][mi] = z;
            }
        }

        // register-resident online softmax in log2 domain (q = mi*16+m15)
        float scl[4];
#pragma unroll
        for (int mi = 0; mi < 4; ++mi) {
            float mx = -INFINITY;
#pragma unroll
            for (int km = 0; km < 4; ++km)
#pragma unroll
                for (int r = 0; r < 4; ++r) mx = fmaxf(mx, ST[km][mi][r]);
            mx = fmaxf(mx, __shfl_xor(mx, 16));
            mx = fmaxf(mx, __shfl_xor(mx, 32));
            float mnew = fmaxf(mrun[mi], mx);
            scl[mi] = fexp2(mrun[mi] - mnew);
            mrun[mi] = mnew;
            float rs = 0.f;
#pragma unroll
            for (int km = 0; km < 4; ++km) {
                float p0 = fexp2(ST[km][mi][0] - mnew);
                float p1 = fexp2(ST[km][mi][1] - mnew);
                float p2 = fexp2(ST[km][mi][2] - mnew);
                float p3 = fexp2(ST[km][mi][3] - mnew);
                rs += (p0 + p1) + (p2 + p3);
                h16x2 d0 = __builtin_amdgcn_cvt_pkrtz(p0, p1);
                h16x2 d1 = __builtin_amdgcn_cvt_pkrtz(p2, p3);
                uint2 wv = { __builtin_bit_cast(unsigned, d0),
                             __builtin_bit_cast(unsigned, d1) };
                *(uint2*)&Ps[w][(mi * 16 + m15) * 72 + km * 16 + g * 4] = wv;
            }
            rs += __shfl_xor(rs, 16);
            rs += __shfl_xor(rs, 32);
            lrun[mi] = lrun[mi] * scl[mi] + rs;
        }

        // wave-uniform skip of accO rescale when max didn't move anywhere
        int chg = (scl[0] < 1.f) | (scl[1] < 1.f) | (scl[2] < 1.f) | (scl[3] < 1.f);
        if (__any(chg)) {
#pragma unroll
            for (int mi = 0; mi < 4; ++mi)
#pragma unroll
                for (int i = 0; i < 4; ++i) accO[mi][i] *= scl[mi];
        }

        // P^T B-frags (per-wave LDS, intra-wave ordering only)
        f16x8 pf[4][2];
#pragma unroll
        for (int mi = 0; mi < 4; ++mi) {
            pf[mi][0] = *(const f16x8*)&Ps[w][(mi * 16 + m15) * 72 + g * 8];
            pf[mi][1] = *(const f16x8*)&Ps[w][(mi * 16 + m15) * 72 + 32 + g * 8];
        }

        // O^T += V^T·P^T
#pragma unroll
        for (int i = 0; i < 4; ++i) {
            const int row = i * 16 + m15;
            f16x8 vf0 = *(const f16x8*)&VTs[row * 64 + ((0 + g) ^ (row & 7)) * 8];
            f16x8 vf1 = *(const f16x8*)&VTs[row * 64 + ((4 + g) ^ (row & 7)) * 8];
#pragma unroll
            for (int mi = 0; mi < 4; ++mi) {
                f32x4 a = accO[mi][i];
                a = __builtin_amdgcn_mfma_f32_16x16x32_f16(vf0, pf[mi][0], a, 0, 0, 0);
                a = __builtin_amdgcn_mfma_f32_16x16x32_f16(vf1, pf[mi][1], a, 0, 0, 0);
                accO[mi][i] = a;
            }
        }
    }

    // epilogue: O^T row d=i*16+g*4+r, col q=mi*16+m15 -> ao[b][s][h*64+d]
#pragma unroll
    for (int mi = 0; mi < 4; ++mi) {
        const float li = 1.f / lrun[mi];
        const size_t qg = rowbase + q0 + mi * 16 + m15;
#pragma unroll
        for (int i = 0; i < 4; ++i) {
            us4 o = { f2h(accO[mi][i][0] * li), f2h(accO[mi][i][1] * li),
                      f2h(accO[mi][i][2] * li), f2h(accO[mi][i][3] * li) };
            *(us4*)(ao + qg * D_MODEL + h * DK + i * 16 + g * 4) = o;
        }
    }
}

// ---------------------------------------------------------------------------
extern "C" void kernel_launch(void* const* d_in, const int* in_sizes, int n_in,
                              void* d_out, int out_size, void* d_ws, size_t ws_size,
                              hipStream_t stream)
{
    const float* Q  = (const float*)d_in[0];
    const float* K  = (const float*)d_in[1];
    const float* V  = (const float*)d_in[2];
    const float* Wq = (const float*)d_in[3];
    const float* Wk = (const float*)d_in[4];
    const float* Wv = (const float*)d_in[5];
    const float* Wo = (const float*)d_in[6];

    unsigned short* base = (unsigned short*)d_ws;
    unsigned short* qb = base;
    unsigned short* kb = qb + TENS;
    unsigned short* vb = kb + TENS;
    unsigned short* wq = vb + TENS;
    unsigned short* wk = wq + WELT;
    unsigned short* wv = wk + WELT;
    unsigned short* wo = wv + WELT;
    unsigned short* qproj = wo + WELT;
    unsigned short* kproj = qproj + TENS;
    unsigned short* vtw   = kproj + TENS;    // [B,H,DK,S]
    unsigned short* aow   = vtw + TENS;

    convert_kernel<<<dim3(TENS / 1024, 7), 256, 0, stream>>>(Q, K, V, Wq, Wk, Wv, Wo, base);

    proj3_kernel<<<dim3(MROWS / 128, D_MODEL / 128, 3), 256, 0, stream>>>(
        qb, kb, vb, wq, wk, wv, qproj, kproj, vtw);

    attn_kernel<<<dim3(SEQ / 256, NHEADS, BATCH), 256, 0, stream>>>(
        qproj, kproj, vtw, aow);

    gemm_out_kernel<<<dim3(MROWS / 128, D_MODEL / 128), 256, 0, stream>>>(
        aow, wo, (float*)d_out);
}